// Round 7
// baseline (150.560 us; speedup 1.0000x reference)
//
#include <hip/hip_runtime.h>
#include <hip/hip_bf16.h>

#define SEQ   64
#define BATCH 8192
#define OBS   47
#define HID   64
#define MLPH  32
#define ACT   12

#define BT 16            // batch rows per workgroup
#define NT 512           // 8 waves: 0-3 heavy, 4-7 light x-GEMM (4:+MLP, 5-7:+obs)
#define NWG (BATCH / BT)

// LDS layout (bytes)
#define XS0O 0           // x ping-pong [16][64] bf16 swz, 2048 each
#define XS1O 2048
#define HM0O 4096        // unmasked h ping-pong [16][64] bf16 swz, 2048 each
#define HM1O 6144
#define XA0O 8192        // xacc ping-pong [p=256][r=16] f32 swzXF, 16384 each
#define XA1O 24576
#define M2OO 40960       // wave-4 ELU scratch [16][32] bf16 swzM, 1024
#define MSKO 41984       // masks [64][16] f32, 4096
#define W1LO 46080       // W1 frag table 4*64*16B
#define W2LO 50176       // W2 frag table 64*16B
#define SMEM_BYTES 51200

typedef __attribute__((ext_vector_type(8))) short short8;
typedef __attribute__((ext_vector_type(4))) float f32x4;

__device__ __forceinline__ ushort f2bf(float f) {
  union { float f; unsigned u; } v; v.f = f;
  return (ushort)((v.u + 0x7FFFu + ((v.u >> 16) & 1u)) >> 16);
}
__device__ __forceinline__ float sigf(float x) { return 1.0f / (1.0f + __expf(-x)); }
__device__ __forceinline__ float tanhfast(float x) { return 1.0f - 2.0f / (1.0f + __expf(2.0f * x)); }

// XOR swizzles (bijective)
__device__ __forceinline__ int swz (int r, int ks) { return (r * 128 + ks * 2) ^ ((r & 7) << 4); }
__device__ __forceinline__ int swzM(int r, int cs) { return (r * 64  + cs * 2) ^ ((r & 7) << 4); }
// xacc f32 [p][16]: 64B row, 4 slots of 16B; spread via p low bits
__device__ __forceinline__ int swzXF(int p, int rq) {
  return p * 64 + ((((rq ^ (p & 3)) << 4)) ^ (((p >> 2) & 1) << 5));
}

extern "C" __global__ void __launch_bounds__(NT)
__attribute__((amdgpu_waves_per_eu(4, 4)))
lstm_policy(const float* __restrict__ obs, const float* __restrict__ h0,
            const float* __restrict__ c0, const float* __restrict__ Wih,
            const float* __restrict__ Whh, const float* __restrict__ bih,
            const float* __restrict__ bhh, const float* __restrict__ W1,
            const float* __restrict__ b1, const float* __restrict__ W2,
            const float* __restrict__ b2, const int* __restrict__ masks,
            float* __restrict__ out)
{
  __shared__ __align__(16) char sm[SMEM_BYTES];
  const int tid  = threadIdx.x;
  const int b0   = blockIdx.x * BT;
  const int lane = tid & 63;
  const int w    = tid >> 6;          // 0..7
  const int lr   = lane & 15;
  const int lg   = lane >> 4;         // 0..3
  const int j    = (w & 3) * 16 + lr;

  // ---------------- phase 0: zero XS, stage masks + MLP weight tables ----------------
  for (int idx = tid; idx < 256; idx += NT)          // XS0+XS1 = 4096 B
    *(f32x4*)(sm + idx * 16) = (f32x4){0.f, 0.f, 0.f, 0.f};
  for (int idx = tid; idx < SEQ * BT; idx += NT) {
    int t = idx >> 4, r = idx & 15;
    *(float*)(sm + MSKO + idx * 4) = (float)masks[t * BATCH + b0 + r];
  }
  if (tid < 64) {
    int l = tid, llr = l & 15, llg = l >> 4;
    #pragma unroll
    for (int tt = 0; tt < 2; ++tt)
      #pragma unroll
      for (int kk = 0; kk < 2; ++kk) {
        short8 f;
        const float* src = W1 + (tt * 16 + llr) * HID + kk * 32 + llg * 8;
        #pragma unroll
        for (int e = 0; e < 8; ++e) f[e] = (short)f2bf(src[e]);
        *(short8*)(sm + W1LO + ((tt * 2 + kk) * 64 + l) * 16) = f;
      }
    short8 f2;
    #pragma unroll
    for (int e = 0; e < 8; ++e)
      f2[e] = (llr < ACT) ? (short)f2bf(W2[llr * MLPH + llg * 8 + e]) : (short)0;
    *(short8*)(sm + W2LO + l * 16) = f2;
  }
  __syncthreads();

  // ---------------- phase 1: register builds + initial staging ----------------
  short8 wf[4][2];                 // heavy: Whh frags ; light: Wih frags
  float biasg[4] = {0, 0, 0, 0};
  float creg[4] = {0, 0, 0, 0}, hlast[4] = {0, 0, 0, 0};

  // per-parity LDS addresses, hoisted once (loop-invariant)
  const int aHMr0[2] = {HM0O + swz(lr, lg * 8),      HM1O + swz(lr, lg * 8)};
  const int aHMr1[2] = {HM0O + swz(lr, 32 + lg * 8), HM1O + swz(lr, 32 + lg * 8)};
  int aXAr[2][4], aHMw[2][4];      // heavy
  int aXSr[2][2], aXAw[2][4];      // light

  if (w < 4) {
    #pragma unroll
    for (int nf = 0; nf < 4; ++nf) {
      int n = nf * 64 + j;
      #pragma unroll
      for (int kk = 0; kk < 2; ++kk) {
        const float* src = Whh + n * HID + kk * 32 + lg * 8;
        short8 f;
        #pragma unroll
        for (int e = 0; e < 8; ++e) f[e] = (short)f2bf(src[e]);
        wf[nf][kk] = f;
      }
      int sx = swzXF(w * 64 + nf * 16 + lr, lg);
      aXAr[0][nf] = XA0O + sx;  aXAr[1][nf] = XA1O + sx;
    }
    #pragma unroll
    for (int q = 0; q < 4; ++q) {
      int r = lg * 4 + q;
      int sh = swz(r, j);
      aHMw[0][q] = HM0O + sh;  aHMw[1][q] = HM1O + sh;
      creg[q] = c0[(size_t)(b0 + r) * HID + j];                     // unmasked
      *(ushort*)(sm + HM0O + sh) = f2bf(h0[(size_t)(b0 + r) * HID + j]);  // unmasked
    }
  } else {
    #pragma unroll
    for (int nf = 0; nf < 4; ++nf) {
      int n = nf * 64 + j;
      biasg[nf] = bih[n] + bhh[n];
      #pragma unroll
      for (int kk = 0; kk < 2; ++kk) {
        short8 f;
        #pragma unroll
        for (int e = 0; e < 8; ++e) {
          int k = kk * 32 + lg * 8 + e;
          f[e] = (k < OBS) ? (short)f2bf(Wih[n * OBS + k]) : (short)0;
        }
        wf[nf][kk] = f;
      }
      int sx = swzXF((w & 3) * 64 + nf * 16 + lr, lg);
      aXAw[0][nf] = XA0O + sx;  aXAw[1][nf] = XA1O + sx;
    }
    aXSr[0][0] = XS0O + swz(lr, lg * 8);  aXSr[0][1] = XS0O + swz(lr, 32 + lg * 8);
    aXSr[1][0] = XS1O + swz(lr, lg * 8);  aXSr[1][1] = XS1O + swz(lr, 32 + lg * 8);
  }

  float b1v0 = 0.f, b1v1 = 0.f, b2v = 0.f;
  float* outp = out + ((size_t)(b0 + lg * 4)) * ACT + lr;   // wave-4 running out ptr
  if (w == 4) { b1v0 = b1[lr]; b1v1 = b1[16 + lr]; b2v = (lr < ACT) ? b2[lr] : 0.f; }

  // obs staging lanes: waves 5-7, 188 slots of f32x4 cover 16*47 floats
  const int oidx = tid - 320;
  const bool oact = (w >= 5) && (oidx >= 0) && (oidx < 188);
  int a_obs[4] = {0, 0, 0, 0};
  f32x4 ovh = {0.f, 0.f, 0.f, 0.f};
  const float* obsp = obs;
  if (oact) {
    #pragma unroll
    for (int e = 0; e < 4; ++e) {
      int flat = oidx * 4 + e;
      int r = flat / OBS, k = flat - OBS * r;
      a_obs[e] = swz(r, k);
    }
    f32x4 v0 = *(const f32x4*)(obs + (size_t)b0 * OBS + oidx * 4);               // x(0)
    f32x4 v1 = *(const f32x4*)(obs + ((size_t)BATCH + b0) * OBS + oidx * 4);     // x(1)
    #pragma unroll
    for (int e = 0; e < 4; ++e) *(ushort*)(sm + XS0O + a_obs[e]) = f2bf(v0[e]);
    #pragma unroll
    for (int e = 0; e < 4; ++e) *(ushort*)(sm + XS1O + a_obs[e]) = f2bf(v1[e]);
    obsp = obs + ((size_t)2 * BATCH + b0) * OBS + oidx * 4;
    ovh = *(const f32x4*)(obsp);                                                 // x(2)
    obsp += (size_t)BATCH * OBS;
  }
  __syncthreads();

  // ---------------- light x-GEMM: xacc(buf B) = x@Wih^T + b (f32) ----------------
  auto do_xgemm = [&](int B) {
    short8 ax0 = *(const short8*)(sm + aXSr[B][0]);
    short8 ax1 = *(const short8*)(sm + aXSr[B][1]);
    #pragma unroll
    for (int nf = 0; nf < 4; ++nf) {
      f32x4 a = (f32x4){biasg[nf], biasg[nf], biasg[nf], biasg[nf]};
      a = __builtin_amdgcn_mfma_f32_16x16x32_bf16(ax0, wf[nf][0], a, 0, 0, 0);
      a = __builtin_amdgcn_mfma_f32_16x16x32_bf16(ax1, wf[nf][1], a, 0, 0, 0);
      *(f32x4*)(sm + aXAw[B][nf]) = a;
    }
  };

  if (w >= 4) do_xgemm(0);    // xacc(0)
  __syncthreads();

  // ---------------- MLP (wave 4): means(TOUT) from HM[P] ----------------
  auto do_mlp = [&](int P) {
    short8 hf0 = *(const short8*)(sm + aHMr0[P]);
    short8 hf1 = *(const short8*)(sm + aHMr1[P]);
    f32x4 am0 = (f32x4){b1v0, b1v0, b1v0, b1v0};
    f32x4 am1 = (f32x4){b1v1, b1v1, b1v1, b1v1};
    short8 wA;
    wA = *(const short8*)(sm + W1LO + (0 * 64 + lane) * 16);
    am0 = __builtin_amdgcn_mfma_f32_16x16x32_bf16(hf0, wA, am0, 0, 0, 0);
    wA = *(const short8*)(sm + W1LO + (1 * 64 + lane) * 16);
    am0 = __builtin_amdgcn_mfma_f32_16x16x32_bf16(hf1, wA, am0, 0, 0, 0);
    wA = *(const short8*)(sm + W1LO + (2 * 64 + lane) * 16);
    am1 = __builtin_amdgcn_mfma_f32_16x16x32_bf16(hf0, wA, am1, 0, 0, 0);
    wA = *(const short8*)(sm + W1LO + (3 * 64 + lane) * 16);
    am1 = __builtin_amdgcn_mfma_f32_16x16x32_bf16(hf1, wA, am1, 0, 0, 0);
    #pragma unroll
    for (int q = 0; q < 4; ++q) {
      int r = lg * 4 + q;
      float v0 = am0[q], v1 = am1[q];
      float e0 = v0 > 0.f ? v0 : (__expf(v0) - 1.f);
      float e1 = v1 > 0.f ? v1 : (__expf(v1) - 1.f);
      *(ushort*)(sm + M2OO + swzM(r, lr))      = f2bf(e0);
      *(ushort*)(sm + M2OO + swzM(r, 16 + lr)) = f2bf(e1);
    }
    f32x4 a2 = (f32x4){b2v, b2v, b2v, b2v};   // same-wave LDS RAW: in-order DS
    short8 ef  = *(const short8*)(sm + M2OO + swzM(lr, lg * 8));
    short8 w2f = *(const short8*)(sm + W2LO + lane * 16);
    a2 = __builtin_amdgcn_mfma_f32_16x16x32_bf16(ef, w2f, a2, 0, 0, 0);
    if (lr < ACT) {
      #pragma unroll
      for (int q = 0; q < 4; ++q) outp[q * ACT] = a2[q];
    }
    outp += (size_t)BATCH * ACT;
  };

  // ---------------- one step (parity P = T&1): ONE barrier ----------------
  // heavy: reads HM[P], XA[P]; writes HM[P^1].  mask m(T) applied post-MFMA.
  // light: xgemm XS[P^1]->XA[P^1]; wave4 MLP(T-1) from HM[P]; obs commit XS[P].
  auto do_step = [&](int P, int T) {
    if (w < 4) {
      short8 ah0 = *(const short8*)(sm + aHMr0[P]);
      short8 ah1 = *(const short8*)(sm + aHMr1[P]);
      f32x4 xq0 = *(const f32x4*)(sm + aXAr[P][0]);
      f32x4 xq1 = *(const f32x4*)(sm + aXAr[P][1]);
      f32x4 xq2 = *(const f32x4*)(sm + aXAr[P][2]);
      f32x4 xq3 = *(const f32x4*)(sm + aXAr[P][3]);
      const f32x4 z = {0.f, 0.f, 0.f, 0.f};
      f32x4 ha0 = z, ha1 = z, ha2 = z, ha3 = z;
      ha0 = __builtin_amdgcn_mfma_f32_16x16x32_bf16(ah0, wf[0][0], ha0, 0, 0, 0);
      ha1 = __builtin_amdgcn_mfma_f32_16x16x32_bf16(ah0, wf[1][0], ha1, 0, 0, 0);
      ha2 = __builtin_amdgcn_mfma_f32_16x16x32_bf16(ah0, wf[2][0], ha2, 0, 0, 0);
      ha3 = __builtin_amdgcn_mfma_f32_16x16x32_bf16(ah0, wf[3][0], ha3, 0, 0, 0);
      ha0 = __builtin_amdgcn_mfma_f32_16x16x32_bf16(ah1, wf[0][1], ha0, 0, 0, 0);
      ha1 = __builtin_amdgcn_mfma_f32_16x16x32_bf16(ah1, wf[1][1], ha1, 0, 0, 0);
      ha2 = __builtin_amdgcn_mfma_f32_16x16x32_bf16(ah1, wf[2][1], ha2, 0, 0, 0);
      ha3 = __builtin_amdgcn_mfma_f32_16x16x32_bf16(ah1, wf[3][1], ha3, 0, 0, 0);

      f32x4 mc = *(const f32x4*)(sm + MSKO + (T << 6) + lg * 16);   // m(T)
      #pragma unroll
      for (int q = 0; q < 4; ++q) {
        float m  = mc[q];
        float g0 = xq0[q] + m * ha0[q];
        float g1 = xq1[q] + m * ha1[q];
        float g2 = xq2[q] + m * ha2[q];
        float g3 = xq3[q] + m * ha3[q];
        float iv = sigf(g0);
        float fv = sigf(g1);
        float gv = tanhfast(g2);
        float ov = sigf(g3);
        float c  = fv * (creg[q] * m) + iv * gv;
        float h  = ov * tanhfast(c);
        creg[q]  = c;                       // unmasked
        hlast[q] = h;
        *(ushort*)(sm + aHMw[P ^ 1][q]) = f2bf(h);   // unmasked h(T)
      }
    } else {
      if (T + 1 < SEQ) do_xgemm(P ^ 1);
      if (w == 4) {
        if (T > 0) do_mlp(P);               // means(T-1)
      } else if (oact) {
        f32x4 ovn = ovh;
        if (T + 3 < SEQ) { ovn = *(const f32x4*)(obsp); }
        obsp += (size_t)BATCH * OBS;
        if (T + 2 < SEQ) {
          #pragma unroll
          for (int e = 0; e < 4; ++e)
            *(ushort*)(sm + (P ? XS1O : XS0O) + a_obs[e]) = f2bf(ovh[e]);
        }
        ovh = ovn;
      }
    }
    __syncthreads();
  };

  for (int t = 0; t < SEQ; t += 2) {
    do_step(0, t);
    do_step(1, t + 1);
  }
  if (w == 4) do_mlp(0);      // means(63): h(63) is in HM0

  // ---------------- final h, c ----------------
  if (w < 4) {
    float* hout = out + (size_t)SEQ * BATCH * ACT;
    float* cout = hout + (size_t)BATCH * HID;
    #pragma unroll
    for (int q = 0; q < 4; ++q) {
      int r = lg * 4 + q;
      hout[(size_t)(b0 + r) * HID + j] = hlast[q];   // h(63) unmasked
      cout[(size_t)(b0 + r) * HID + j] = creg[q];    // c(63) unmasked
    }
  }
}

extern "C" void kernel_launch(void* const* d_in, const int* in_sizes, int n_in,
                              void* d_out, int out_size, void* d_ws, size_t ws_size,
                              hipStream_t stream) {
  (void)in_sizes; (void)n_in; (void)d_ws; (void)ws_size; (void)out_size;
  lstm_policy<<<dim3(NWG), dim3(NT), 0, stream>>>(
      (const float*)d_in[0], (const float*)d_in[1], (const float*)d_in[2],
      (const float*)d_in[3], (const float*)d_in[4], (const float*)d_in[5],
      (const float*)d_in[6], (const float*)d_in[7], (const float*)d_in[8],
      (const float*)d_in[9], (const float*)d_in[10], (const int*)d_in[11],
      (float*)d_out);
}

// Round 9
// 131.157 us; speedup vs baseline: 1.1479x; 1.1479x over previous
//
#include <hip/hip_runtime.h>
#include <hip/hip_bf16.h>

#define SEQ   64
#define BATCH 8192
#define OBS   47
#define HID   64
#define MLPH  32
#define ACT   12

#define BT 16            // batch rows per workgroup
#define NT 512           // 8 waves: 0-3 heavy (h-GEMM+cell), 4-7 light (x-GEMM; 4:+MLP, 5-7:+obs)
#define NWG (BATCH / BT) // 512 workgroups -> 2 per CU

// LDS layout (bytes)
#define XS0O 0           // x ping-pong [16][64] bf16 swz, 2048 each
#define XS1O 2048
#define HM0O 4096        // unmasked h ping-pong [16][64] bf16 swz, 2048 each
#define HM1O 6144
#define XA0O 8192        // xacc ping-pong [p=256][r=16] bf16 swzX, 8192 each
#define XA1O 16384
#define M2OO 24576       // wave-4 ELU scratch [16][32] bf16 swzM, 1024
#define MSKO 25600       // masks [64][16] f32, 4096
#define W1LO 29696       // W1 frag table 4*64*16B = 4096
#define W2LO 33792       // W2 frag table 64*16B = 1024
#define SMEM_BYTES 34816

typedef __attribute__((ext_vector_type(8))) short short8;
typedef __attribute__((ext_vector_type(4))) short short4v;
typedef __attribute__((ext_vector_type(4))) float f32x4;

__device__ __forceinline__ ushort f2bf(float f) {
  union { float f; unsigned u; } v; v.f = f;
  return (ushort)((v.u + 0x7FFFu + ((v.u >> 16) & 1u)) >> 16);
}
__device__ __forceinline__ float bf2f(ushort u) {
  union { float f; unsigned u; } v; v.u = (unsigned)u << 16; return v.f;
}
// fast activations: __fdividef = rcp+mul (no div_scale sequence), __expf = v_exp
__device__ __forceinline__ float sigf(float x)      { return __fdividef(1.0f, 1.0f + __expf(-x)); }
__device__ __forceinline__ float tanhfast(float x)  { return 1.0f - __fdividef(2.0f, 1.0f + __expf(2.0f * x)); }

// XOR swizzles (bijective)
__device__ __forceinline__ int swz (int r, int ks) { return (r * 128 + ks * 2) ^ ((r & 7) << 4); }
__device__ __forceinline__ int swzM(int r, int cs) { return (r * 64  + cs * 2) ^ ((r & 7) << 4); }
// xacc bf16 [p][4 slots of 8B]; spread via p bits 2-3
__device__ __forceinline__ int swzX(int p, int rq) { return p * 32 + ((rq ^ ((p >> 2) & 3)) << 3); }

extern "C" __global__ void __launch_bounds__(NT, 4)
lstm_policy(const float* __restrict__ obs, const float* __restrict__ h0,
            const float* __restrict__ c0, const float* __restrict__ Wih,
            const float* __restrict__ Whh, const float* __restrict__ bih,
            const float* __restrict__ bhh, const float* __restrict__ W1,
            const float* __restrict__ b1, const float* __restrict__ W2,
            const float* __restrict__ b2, const int* __restrict__ masks,
            float* __restrict__ out)
{
  __shared__ __align__(16) char sm[SMEM_BYTES];
  const int tid  = threadIdx.x;
  const int b0   = blockIdx.x * BT;
  const int lane = tid & 63;
  const int w    = tid >> 6;          // 0..7
  const int lr   = lane & 15;
  const int lg   = lane >> 4;         // 0..3
  const int j    = (w & 3) * 16 + lr;

  // ---------------- phase 0: zero XS, stage masks + MLP weight tables ----------------
  for (int idx = tid; idx < 256; idx += NT)          // XS0+XS1 = 4096 B
    *(f32x4*)(sm + idx * 16) = (f32x4){0.f, 0.f, 0.f, 0.f};
  for (int idx = tid; idx < SEQ * BT; idx += NT) {
    int t = idx >> 4, r = idx & 15;
    *(float*)(sm + MSKO + idx * 4) = (float)masks[t * BATCH + b0 + r];
  }
  if (tid < 64) {
    int l = tid, llr = l & 15, llg = l >> 4;
    #pragma unroll
    for (int tt = 0; tt < 2; ++tt)
      #pragma unroll
      for (int kk = 0; kk < 2; ++kk) {
        short8 f;
        const float* src = W1 + (tt * 16 + llr) * HID + kk * 32 + llg * 8;
        #pragma unroll
        for (int e = 0; e < 8; ++e) f[e] = (short)f2bf(src[e]);
        *(short8*)(sm + W1LO + ((tt * 2 + kk) * 64 + l) * 16) = f;
      }
    short8 f2;
    #pragma unroll
    for (int e = 0; e < 8; ++e)
      f2[e] = (llr < ACT) ? (short)f2bf(W2[llr * MLPH + llg * 8 + e]) : (short)0;
    *(short8*)(sm + W2LO + l * 16) = f2;
  }
  __syncthreads();

  // ---------------- phase 1: register builds + initial staging ----------------
  short8 wf[4][2];                 // heavy: Whh frags ; light: Wih frags
  float biasg[4] = {0, 0, 0, 0};
  float creg[4] = {0, 0, 0, 0}, hlast[4] = {0, 0, 0, 0};
  int shw[4];                      // h-write swizzled offsets (parity-independent part)
  #pragma unroll
  for (int q = 0; q < 4; ++q) shw[q] = swz(lg * 4 + q, j);

  if (w < 4) {
    #pragma unroll
    for (int nf = 0; nf < 4; ++nf) {
      int n = nf * 64 + j;
      #pragma unroll
      for (int kk = 0; kk < 2; ++kk) {
        const float* src = Whh + n * HID + kk * 32 + lg * 8;
        short8 f;
        #pragma unroll
        for (int e = 0; e < 8; ++e) f[e] = (short)f2bf(src[e]);
        wf[nf][kk] = f;
      }
    }
    #pragma unroll
    for (int q = 0; q < 4; ++q) {
      int r = lg * 4 + q;
      creg[q] = c0[(size_t)(b0 + r) * HID + j];                               // unmasked
      *(ushort*)(sm + HM0O + shw[q]) = f2bf(h0[(size_t)(b0 + r) * HID + j]);  // unmasked
    }
  } else {
    #pragma unroll
    for (int nf = 0; nf < 4; ++nf) {
      int n = nf * 64 + j;
      biasg[nf] = bih[n] + bhh[n];
      #pragma unroll
      for (int kk = 0; kk < 2; ++kk) {
        short8 f;
        #pragma unroll
        for (int e = 0; e < 8; ++e) {
          int k = kk * 32 + lg * 8 + e;
          f[e] = (k < OBS) ? (short)f2bf(Wih[n * OBS + k]) : (short)0;
        }
        wf[nf][kk] = f;
      }
    }
  }

  float b1v0 = 0.f, b1v1 = 0.f, b2v = 0.f;
  float* outp = out + ((size_t)(b0 + lg * 4)) * ACT + lr;   // wave-4 running out ptr
  if (w == 4) { b1v0 = b1[lr]; b1v1 = b1[16 + lr]; b2v = (lr < ACT) ? b2[lr] : 0.f; }

  // obs staging lanes: waves 5-7, 188 slots of f32x4 cover 16*47 floats
  const int oidx = tid - 320;
  const bool oact = (w >= 5) && (oidx >= 0) && (oidx < 188);
  int a_obs[4] = {0, 0, 0, 0};
  f32x4 ovh = {0.f, 0.f, 0.f, 0.f};
  const float* obsp = obs;
  if (oact) {
    #pragma unroll
    for (int e = 0; e < 4; ++e) {
      int flat = oidx * 4 + e;
      int r = flat / OBS, k = flat - OBS * r;
      a_obs[e] = swz(r, k);
    }
    f32x4 v0 = *(const f32x4*)(obs + (size_t)b0 * OBS + oidx * 4);               // x(0)
    f32x4 v1 = *(const f32x4*)(obs + ((size_t)BATCH + b0) * OBS + oidx * 4);     // x(1)
    #pragma unroll
    for (int e = 0; e < 4; ++e) *(ushort*)(sm + XS0O + a_obs[e]) = f2bf(v0[e]);
    #pragma unroll
    for (int e = 0; e < 4; ++e) *(ushort*)(sm + XS1O + a_obs[e]) = f2bf(v1[e]);
    obsp = obs + ((size_t)2 * BATCH + b0) * OBS + oidx * 4;
    ovh = *(const f32x4*)(obsp);                                                 // x(2)
    obsp += (size_t)BATCH * OBS;
  }
  __syncthreads();

  // ---------------- light x-GEMM: xacc(buf B) = x@Wih^T + b, bf16 ----------------
  auto do_xgemm = [&](int B) {
    const int xsb = B ? XS1O : XS0O;
    const int xab = B ? XA1O : XA0O;
    short8 ax0 = *(const short8*)(sm + xsb + swz(lr, lg * 8));
    short8 ax1 = *(const short8*)(sm + xsb + swz(lr, 32 + lg * 8));
    #pragma unroll
    for (int nf = 0; nf < 4; ++nf) {
      f32x4 a = (f32x4){biasg[nf], biasg[nf], biasg[nf], biasg[nf]};
      a = __builtin_amdgcn_mfma_f32_16x16x32_bf16(ax0, wf[nf][0], a, 0, 0, 0);
      a = __builtin_amdgcn_mfma_f32_16x16x32_bf16(ax1, wf[nf][1], a, 0, 0, 0);
      short4v o;
      #pragma unroll
      for (int q = 0; q < 4; ++q) o[q] = (short)f2bf(a[q]);
      *(short4v*)(sm + xab + swzX((w & 3) * 64 + nf * 16 + lr, lg)) = o;
    }
  };

  if (w >= 4) do_xgemm(0);    // xacc(0)
  __syncthreads();

  // ---------------- MLP (wave 4): means from HM[P] ----------------
  auto do_mlp = [&](int P) {
    const int hmb = P ? HM1O : HM0O;
    short8 hf0 = *(const short8*)(sm + hmb + swz(lr, lg * 8));
    short8 hf1 = *(const short8*)(sm + hmb + swz(lr, 32 + lg * 8));
    f32x4 am0 = (f32x4){b1v0, b1v0, b1v0, b1v0};
    f32x4 am1 = (f32x4){b1v1, b1v1, b1v1, b1v1};
    short8 wA;
    wA = *(const short8*)(sm + W1LO + (0 * 64 + lane) * 16);
    am0 = __builtin_amdgcn_mfma_f32_16x16x32_bf16(hf0, wA, am0, 0, 0, 0);
    wA = *(const short8*)(sm + W1LO + (1 * 64 + lane) * 16);
    am0 = __builtin_amdgcn_mfma_f32_16x16x32_bf16(hf1, wA, am0, 0, 0, 0);
    wA = *(const short8*)(sm + W1LO + (2 * 64 + lane) * 16);
    am1 = __builtin_amdgcn_mfma_f32_16x16x32_bf16(hf0, wA, am1, 0, 0, 0);
    wA = *(const short8*)(sm + W1LO + (3 * 64 + lane) * 16);
    am1 = __builtin_amdgcn_mfma_f32_16x16x32_bf16(hf1, wA, am1, 0, 0, 0);
    #pragma unroll
    for (int q = 0; q < 4; ++q) {
      int r = lg * 4 + q;
      float v0 = am0[q], v1 = am1[q];
      float e0 = v0 > 0.f ? v0 : (__expf(v0) - 1.f);
      float e1 = v1 > 0.f ? v1 : (__expf(v1) - 1.f);
      *(ushort*)(sm + M2OO + swzM(r, lr))      = f2bf(e0);
      *(ushort*)(sm + M2OO + swzM(r, 16 + lr)) = f2bf(e1);
    }
    f32x4 a2 = (f32x4){b2v, b2v, b2v, b2v};   // same-wave LDS RAW: in-order DS
    short8 ef  = *(const short8*)(sm + M2OO + swzM(lr, lg * 8));
    short8 w2f = *(const short8*)(sm + W2LO + lane * 16);
    a2 = __builtin_amdgcn_mfma_f32_16x16x32_bf16(ef, w2f, a2, 0, 0, 0);
    if (lr < ACT) {
      #pragma unroll
      for (int q = 0; q < 4; ++q) outp[q * ACT] = a2[q];
    }
    outp += (size_t)BATCH * ACT;
  };

  // ---------------- one step (parity P = T&1): ONE barrier ----------------
  // heavy: reads HM[P] (=h(T-1)), XA[P]; writes HM[P^1] (=h(T)); mask m(T) post-MFMA.
  // light: xgemm XS[P^1]->XA[P^1]; wave4 MLP(T-1) from HM[P]; obs commit x(T+2)->XS[P].
  auto do_step = [&](int P, int T) {
    if (w < 4) {
      const int hmr = P ? HM1O : HM0O;
      const int hmw = P ? HM0O : HM1O;
      const int xar = P ? XA1O : XA0O;
      short8 ah0 = *(const short8*)(sm + hmr + swz(lr, lg * 8));
      short8 ah1 = *(const short8*)(sm + hmr + swz(lr, 32 + lg * 8));
      short4v x0 = *(const short4v*)(sm + xar + swzX(w * 64 +  0 + lr, lg));
      short4v x1 = *(const short4v*)(sm + xar + swzX(w * 64 + 16 + lr, lg));
      short4v x2 = *(const short4v*)(sm + xar + swzX(w * 64 + 32 + lr, lg));
      short4v x3 = *(const short4v*)(sm + xar + swzX(w * 64 + 48 + lr, lg));
      const f32x4 z = {0.f, 0.f, 0.f, 0.f};
      f32x4 ha0 = z, ha1 = z, ha2 = z, ha3 = z;
      ha0 = __builtin_amdgcn_mfma_f32_16x16x32_bf16(ah0, wf[0][0], ha0, 0, 0, 0);
      ha1 = __builtin_amdgcn_mfma_f32_16x16x32_bf16(ah0, wf[1][0], ha1, 0, 0, 0);
      ha2 = __builtin_amdgcn_mfma_f32_16x16x32_bf16(ah0, wf[2][0], ha2, 0, 0, 0);
      ha3 = __builtin_amdgcn_mfma_f32_16x16x32_bf16(ah0, wf[3][0], ha3, 0, 0, 0);
      ha0 = __builtin_amdgcn_mfma_f32_16x16x32_bf16(ah1, wf[0][1], ha0, 0, 0, 0);
      ha1 = __builtin_amdgcn_mfma_f32_16x16x32_bf16(ah1, wf[1][1], ha1, 0, 0, 0);
      ha2 = __builtin_amdgcn_mfma_f32_16x16x32_bf16(ah1, wf[2][1], ha2, 0, 0, 0);
      ha3 = __builtin_amdgcn_mfma_f32_16x16x32_bf16(ah1, wf[3][1], ha3, 0, 0, 0);

      f32x4 mc = *(const f32x4*)(sm + MSKO + (T << 6) + lg * 16);   // m(T)
      #pragma unroll
      for (int q = 0; q < 4; ++q) {
        float m  = mc[q];
        float g0 = bf2f((ushort)x0[q]) + m * ha0[q];   // i
        float g1 = bf2f((ushort)x1[q]) + m * ha1[q];   // f
        float g2 = bf2f((ushort)x2[q]) + m * ha2[q];   // g
        float g3 = bf2f((ushort)x3[q]) + m * ha3[q];   // o
        float iv = sigf(g0);
        float fv = sigf(g1);
        float gv = tanhfast(g2);
        float ov = sigf(g3);
        float c  = fv * (creg[q] * m) + iv * gv;
        float h  = ov * tanhfast(c);
        creg[q]  = c;                                  // unmasked
        hlast[q] = h;
        *(ushort*)(sm + hmw + shw[q]) = f2bf(h);       // unmasked h(T)
      }
    } else {
      if (T + 1 < SEQ) do_xgemm(P ^ 1);
      if (w == 4) {
        if (T > 0) do_mlp(P);            // means(T-1)
      } else if (oact) {
        f32x4 ovn = ovh;
        if (T + 3 < SEQ) { ovn = *(const f32x4*)(obsp); }
        obsp += (size_t)BATCH * OBS;
        if (T + 2 < SEQ) {
          const int xsw = P ? XS1O : XS0O;
          #pragma unroll
          for (int e = 0; e < 4; ++e)
            *(ushort*)(sm + xsw + a_obs[e]) = f2bf(ovh[e]);
        }
        ovh = ovn;
      }
    }
    __syncthreads();
  };

  for (int t = 0; t < SEQ; t += 2) {
    do_step(0, t);
    do_step(1, t + 1);
  }
  if (w == 4) do_mlp(0);      // means(63): h(63) is in HM0

  // ---------------- final h, c ----------------
  if (w < 4) {
    float* hout = out + (size_t)SEQ * BATCH * ACT;
    float* cout = hout + (size_t)BATCH * HID;
    #pragma unroll
    for (int q = 0; q < 4; ++q) {
      int r = lg * 4 + q;
      hout[(size_t)(b0 + r) * HID + j] = hlast[q];   // h(63) unmasked
      cout[(size_t)(b0 + r) * HID + j] = creg[q];    // c(63) unmasked
    }
  }
}

extern "C" void kernel_launch(void* const* d_in, const int* in_sizes, int n_in,
                              void* d_out, int out_size, void* d_ws, size_t ws_size,
                              hipStream_t stream) {
  (void)in_sizes; (void)n_in; (void)d_ws; (void)ws_size; (void)out_size;
  lstm_policy<<<dim3(NWG), dim3(NT), 0, stream>>>(
      (const float*)d_in[0], (const float*)d_in[1], (const float*)d_in[2],
      (const float*)d_in[3], (const float*)d_in[4], (const float*)d_in[5],
      (const float*)d_in[6], (const float*)d_in[7], (const float*)d_in[8],
      (const float*)d_in[9], (const float*)d_in[10], (const int*)d_in[11],
      (float*)d_out);
}

// Round 10
// 131.039 us; speedup vs baseline: 1.1490x; 1.0009x over previous
//
#include <hip/hip_runtime.h>
#include <hip/hip_bf16.h>

#define SEQ   64
#define BATCH 8192
#define OBS   47
#define HID   64
#define MLPH  32
#define ACT   12

#define BT 16            // batch rows per workgroup
#define NT 512           // 8 waves: 0-3 heavy (h-GEMM+cell), 4-7 light (x-GEMM; 4:+MLP, 5-7:+obs)
#define NWG (BATCH / BT) // 512 workgroups -> 2 per CU

// LDS layout (bytes)
#define XS0O 0           // x ping-pong [16][64] bf16 swz, 2048 each
#define XS1O 2048
#define HM0O 4096        // unmasked h ping-pong [16][64] bf16 swz, 2048 each
#define HM1O 6144
#define XA0O 8192        // xacc ping-pong [p=256][r=16] bf16 swzX, 8192 each
#define XA1O 16384
#define M2OO 24576       // wave-4 ELU scratch [16][32] bf16 swzM, 1024
#define MSKO 25600       // masks [64][16] f32, 4096
#define W1LO 29696       // W1 frag table 4*64*16B = 4096
#define W2LO 33792       // W2 frag table 64*16B = 1024
#define SMEM_BYTES 34816

typedef __attribute__((ext_vector_type(8))) short short8;
typedef __attribute__((ext_vector_type(4))) short short4v;
typedef __attribute__((ext_vector_type(4))) float f32x4;

__device__ __forceinline__ ushort f2bf(float f) {
  union { float f; unsigned u; } v; v.f = f;
  return (ushort)((v.u + 0x7FFFu + ((v.u >> 16) & 1u)) >> 16);
}
__device__ __forceinline__ float bf2f(ushort u) {
  union { float f; unsigned u; } v; v.u = (unsigned)u << 16; return v.f;
}
// fast activations: __fdividef = rcp+mul, __expf = v_exp
__device__ __forceinline__ float sigf(float x)      { return __fdividef(1.0f, 1.0f + __expf(-x)); }
__device__ __forceinline__ float tanhfast(float x)  { return 1.0f - __fdividef(2.0f, 1.0f + __expf(2.0f * x)); }

// loop barrier: LDS visibility only — do NOT drain vmcnt (obs prefetch / out
// stores have no cross-wave consumers; draining them exposes HBM latency
// inside every step — T4 lesson). sched_barrier fences compiler motion (rule #18).
__device__ __forceinline__ void barrier_lgkm() {
  __builtin_amdgcn_sched_barrier(0);
  asm volatile("s_waitcnt lgkmcnt(0)" ::: "memory");
  __builtin_amdgcn_s_barrier();
  __builtin_amdgcn_sched_barrier(0);
}

// XOR swizzles (bijective)
__device__ __forceinline__ int swz (int r, int ks) { return (r * 128 + ks * 2) ^ ((r & 7) << 4); }
__device__ __forceinline__ int swzM(int r, int cs) { return (r * 64  + cs * 2) ^ ((r & 7) << 4); }
// xacc bf16 [p][4 slots of 8B]; spread via p bits 2-3
__device__ __forceinline__ int swzX(int p, int rq) { return p * 32 + ((rq ^ ((p >> 2) & 3)) << 3); }

extern "C" __global__ void __launch_bounds__(NT, 4)
lstm_policy(const float* __restrict__ obs, const float* __restrict__ h0,
            const float* __restrict__ c0, const float* __restrict__ Wih,
            const float* __restrict__ Whh, const float* __restrict__ bih,
            const float* __restrict__ bhh, const float* __restrict__ W1,
            const float* __restrict__ b1, const float* __restrict__ W2,
            const float* __restrict__ b2, const int* __restrict__ masks,
            float* __restrict__ out)
{
  __shared__ __align__(16) char sm[SMEM_BYTES];
  const int tid  = threadIdx.x;
  const int b0   = blockIdx.x * BT;
  const int lane = tid & 63;
  const int w    = tid >> 6;          // 0..7
  const int lr   = lane & 15;
  const int lg   = lane >> 4;         // 0..3
  const int j    = (w & 3) * 16 + lr;

  // ---------------- phase 0: zero XS, stage masks + MLP weight tables ----------------
  for (int idx = tid; idx < 256; idx += NT)          // XS0+XS1 = 4096 B
    *(f32x4*)(sm + idx * 16) = (f32x4){0.f, 0.f, 0.f, 0.f};
  for (int idx = tid; idx < SEQ * BT; idx += NT) {
    int t = idx >> 4, r = idx & 15;
    *(float*)(sm + MSKO + idx * 4) = (float)masks[t * BATCH + b0 + r];
  }
  if (tid < 64) {
    int l = tid, llr = l & 15, llg = l >> 4;
    #pragma unroll
    for (int tt = 0; tt < 2; ++tt)
      #pragma unroll
      for (int kk = 0; kk < 2; ++kk) {
        short8 f;
        const float* src = W1 + (tt * 16 + llr) * HID + kk * 32 + llg * 8;
        #pragma unroll
        for (int e = 0; e < 8; ++e) f[e] = (short)f2bf(src[e]);
        *(short8*)(sm + W1LO + ((tt * 2 + kk) * 64 + l) * 16) = f;
      }
    short8 f2;
    #pragma unroll
    for (int e = 0; e < 8; ++e)
      f2[e] = (llr < ACT) ? (short)f2bf(W2[llr * MLPH + llg * 8 + e]) : (short)0;
    *(short8*)(sm + W2LO + l * 16) = f2;
  }
  __syncthreads();

  // ---------------- phase 1: register builds + initial staging ----------------
  short8 wf[4][2];                 // heavy: Whh frags ; light: Wih frags
  float biasg[4] = {0, 0, 0, 0};
  float creg[4] = {0, 0, 0, 0}, hlast[4] = {0, 0, 0, 0};
  int shw[4];                      // h-write swizzled offsets
  #pragma unroll
  for (int q = 0; q < 4; ++q) shw[q] = swz(lg * 4 + q, j);

  if (w < 4) {
    #pragma unroll
    for (int nf = 0; nf < 4; ++nf) {
      int n = nf * 64 + j;
      #pragma unroll
      for (int kk = 0; kk < 2; ++kk) {
        const float* src = Whh + n * HID + kk * 32 + lg * 8;
        short8 f;
        #pragma unroll
        for (int e = 0; e < 8; ++e) f[e] = (short)f2bf(src[e]);
        wf[nf][kk] = f;
      }
    }
    #pragma unroll
    for (int q = 0; q < 4; ++q) {
      int r = lg * 4 + q;
      creg[q] = c0[(size_t)(b0 + r) * HID + j];                               // unmasked
      *(ushort*)(sm + HM0O + shw[q]) = f2bf(h0[(size_t)(b0 + r) * HID + j]);  // unmasked
    }
  } else {
    #pragma unroll
    for (int nf = 0; nf < 4; ++nf) {
      int n = nf * 64 + j;
      biasg[nf] = bih[n] + bhh[n];
      #pragma unroll
      for (int kk = 0; kk < 2; ++kk) {
        short8 f;
        #pragma unroll
        for (int e = 0; e < 8; ++e) {
          int k = kk * 32 + lg * 8 + e;
          f[e] = (k < OBS) ? (short)f2bf(Wih[n * OBS + k]) : (short)0;
        }
        wf[nf][kk] = f;
      }
    }
  }

  float b1v0 = 0.f, b1v1 = 0.f, b2v = 0.f;
  float* outp = out + ((size_t)(b0 + lg * 4)) * ACT + lr;   // wave-4 running out ptr
  if (w == 4) { b1v0 = b1[lr]; b1v1 = b1[16 + lr]; b2v = (lr < ACT) ? b2[lr] : 0.f; }

  // obs staging lanes: waves 5-7, 188 slots of f32x4 cover 16*47 floats
  const int oidx = tid - 320;
  const bool oact = (w >= 5) && (oidx >= 0) && (oidx < 188);
  int a_obs[4] = {0, 0, 0, 0};
  f32x4 ovh = {0.f, 0.f, 0.f, 0.f};
  const float* obsp = obs;
  if (oact) {
    #pragma unroll
    for (int e = 0; e < 4; ++e) {
      int flat = oidx * 4 + e;
      int r = flat / OBS, k = flat - OBS * r;
      a_obs[e] = swz(r, k);
    }
    f32x4 v0 = *(const f32x4*)(obs + (size_t)b0 * OBS + oidx * 4);               // x(0)
    f32x4 v1 = *(const f32x4*)(obs + ((size_t)BATCH + b0) * OBS + oidx * 4);     // x(1)
    #pragma unroll
    for (int e = 0; e < 4; ++e) *(ushort*)(sm + XS0O + a_obs[e]) = f2bf(v0[e]);
    #pragma unroll
    for (int e = 0; e < 4; ++e) *(ushort*)(sm + XS1O + a_obs[e]) = f2bf(v1[e]);
    obsp = obs + ((size_t)2 * BATCH + b0) * OBS + oidx * 4;
    ovh = *(const f32x4*)(obsp);                                                 // x(2)
    obsp += (size_t)BATCH * OBS;
  }
  __syncthreads();

  // ---------------- light x-GEMM: xacc(buf B) = x@Wih^T + b, bf16 ----------------
  auto do_xgemm = [&](int B) {
    const int xsb = B ? XS1O : XS0O;
    const int xab = B ? XA1O : XA0O;
    short8 ax0 = *(const short8*)(sm + xsb + swz(lr, lg * 8));
    short8 ax1 = *(const short8*)(sm + xsb + swz(lr, 32 + lg * 8));
    #pragma unroll
    for (int nf = 0; nf < 4; ++nf) {
      f32x4 a = (f32x4){biasg[nf], biasg[nf], biasg[nf], biasg[nf]};
      a = __builtin_amdgcn_mfma_f32_16x16x32_bf16(ax0, wf[nf][0], a, 0, 0, 0);
      a = __builtin_amdgcn_mfma_f32_16x16x32_bf16(ax1, wf[nf][1], a, 0, 0, 0);
      short4v o;
      #pragma unroll
      for (int q = 0; q < 4; ++q) o[q] = (short)f2bf(a[q]);
      *(short4v*)(sm + xab + swzX((w & 3) * 64 + nf * 16 + lr, lg)) = o;
    }
  };

  if (w >= 4) do_xgemm(0);    // xacc(0)
  __syncthreads();

  // ---------------- MLP (wave 4): means from HM[P] ----------------
  auto do_mlp = [&](int P) {
    const int hmb = P ? HM1O : HM0O;
    short8 hf0 = *(const short8*)(sm + hmb + swz(lr, lg * 8));
    short8 hf1 = *(const short8*)(sm + hmb + swz(lr, 32 + lg * 8));
    f32x4 am0 = (f32x4){b1v0, b1v0, b1v0, b1v0};
    f32x4 am1 = (f32x4){b1v1, b1v1, b1v1, b1v1};
    short8 wA;
    wA = *(const short8*)(sm + W1LO + (0 * 64 + lane) * 16);
    am0 = __builtin_amdgcn_mfma_f32_16x16x32_bf16(hf0, wA, am0, 0, 0, 0);
    wA = *(const short8*)(sm + W1LO + (1 * 64 + lane) * 16);
    am0 = __builtin_amdgcn_mfma_f32_16x16x32_bf16(hf1, wA, am0, 0, 0, 0);
    wA = *(const short8*)(sm + W1LO + (2 * 64 + lane) * 16);
    am1 = __builtin_amdgcn_mfma_f32_16x16x32_bf16(hf0, wA, am1, 0, 0, 0);
    wA = *(const short8*)(sm + W1LO + (3 * 64 + lane) * 16);
    am1 = __builtin_amdgcn_mfma_f32_16x16x32_bf16(hf1, wA, am1, 0, 0, 0);
    #pragma unroll
    for (int q = 0; q < 4; ++q) {
      int r = lg * 4 + q;
      float v0 = am0[q], v1 = am1[q];
      float e0 = v0 > 0.f ? v0 : (__expf(v0) - 1.f);
      float e1 = v1 > 0.f ? v1 : (__expf(v1) - 1.f);
      *(ushort*)(sm + M2OO + swzM(r, lr))      = f2bf(e0);
      *(ushort*)(sm + M2OO + swzM(r, 16 + lr)) = f2bf(e1);
    }
    f32x4 a2 = (f32x4){b2v, b2v, b2v, b2v};   // same-wave LDS RAW: in-order DS
    short8 ef  = *(const short8*)(sm + M2OO + swzM(lr, lg * 8));
    short8 w2f = *(const short8*)(sm + W2LO + lane * 16);
    a2 = __builtin_amdgcn_mfma_f32_16x16x32_bf16(ef, w2f, a2, 0, 0, 0);
    if (lr < ACT) {
      #pragma unroll
      for (int q = 0; q < 4; ++q) outp[q * ACT] = a2[q];
    }
    outp += (size_t)BATCH * ACT;
  };

  // ---------------- one step (parity P = T&1): ONE lgkm-only barrier ----------------
  // heavy: reads HM[P] (=h(T-1)), XA[P]; writes HM[P^1] (=h(T)); mask m(T) post-MFMA.
  // light: xgemm XS[P^1]->XA[P^1]; wave4 MLP(T-1) from HM[P]; obs commit x(T+2)->XS[P].
  auto do_step = [&](int P, int T) {
    if (w < 4) {
      const int hmr = P ? HM1O : HM0O;
      const int hmw = P ? HM0O : HM1O;
      const int xar = P ? XA1O : XA0O;
      short8 ah0 = *(const short8*)(sm + hmr + swz(lr, lg * 8));
      short8 ah1 = *(const short8*)(sm + hmr + swz(lr, 32 + lg * 8));
      short4v x0 = *(const short4v*)(sm + xar + swzX(w * 64 +  0 + lr, lg));
      short4v x1 = *(const short4v*)(sm + xar + swzX(w * 64 + 16 + lr, lg));
      short4v x2 = *(const short4v*)(sm + xar + swzX(w * 64 + 32 + lr, lg));
      short4v x3 = *(const short4v*)(sm + xar + swzX(w * 64 + 48 + lr, lg));
      const f32x4 z = {0.f, 0.f, 0.f, 0.f};
      f32x4 ha0 = z, ha1 = z, ha2 = z, ha3 = z;
      ha0 = __builtin_amdgcn_mfma_f32_16x16x32_bf16(ah0, wf[0][0], ha0, 0, 0, 0);
      ha1 = __builtin_amdgcn_mfma_f32_16x16x32_bf16(ah0, wf[1][0], ha1, 0, 0, 0);
      ha2 = __builtin_amdgcn_mfma_f32_16x16x32_bf16(ah0, wf[2][0], ha2, 0, 0, 0);
      ha3 = __builtin_amdgcn_mfma_f32_16x16x32_bf16(ah0, wf[3][0], ha3, 0, 0, 0);
      ha0 = __builtin_amdgcn_mfma_f32_16x16x32_bf16(ah1, wf[0][1], ha0, 0, 0, 0);
      ha1 = __builtin_amdgcn_mfma_f32_16x16x32_bf16(ah1, wf[1][1], ha1, 0, 0, 0);
      ha2 = __builtin_amdgcn_mfma_f32_16x16x32_bf16(ah1, wf[2][1], ha2, 0, 0, 0);
      ha3 = __builtin_amdgcn_mfma_f32_16x16x32_bf16(ah1, wf[3][1], ha3, 0, 0, 0);

      f32x4 mc = *(const f32x4*)(sm + MSKO + (T << 6) + lg * 16);   // m(T)
      #pragma unroll
      for (int q = 0; q < 4; ++q) {
        float m  = mc[q];
        float g0 = bf2f((ushort)x0[q]) + m * ha0[q];   // i
        float g1 = bf2f((ushort)x1[q]) + m * ha1[q];   // f
        float g2 = bf2f((ushort)x2[q]) + m * ha2[q];   // g
        float g3 = bf2f((ushort)x3[q]) + m * ha3[q];   // o
        float iv = sigf(g0);
        float fv = sigf(g1);
        float gv = tanhfast(g2);
        float ov = sigf(g3);
        float c  = fv * (creg[q] * m) + iv * gv;
        float h  = ov * tanhfast(c);
        creg[q]  = c;                                  // unmasked
        hlast[q] = h;
        *(ushort*)(sm + hmw + shw[q]) = f2bf(h);       // unmasked h(T)
      }
    } else {
      if (T + 1 < SEQ) do_xgemm(P ^ 1);
      if (w == 4) {
        if (T > 0) do_mlp(P);            // means(T-1)
      } else if (oact) {
        f32x4 ovn = ovh;
        if (T + 3 < SEQ) { ovn = *(const f32x4*)(obsp); }
        obsp += (size_t)BATCH * OBS;
        if (T + 2 < SEQ) {
          const int xsw = P ? XS1O : XS0O;
          #pragma unroll
          for (int e = 0; e < 4; ++e)
            *(ushort*)(sm + xsw + a_obs[e]) = f2bf(ovh[e]);
        }
        ovh = ovn;
      }
    }
    barrier_lgkm();   // LDS-visibility barrier; global loads stay in flight
  };

  for (int t = 0; t < SEQ; t += 2) {
    do_step(0, t);
    do_step(1, t + 1);
  }
  if (w == 4) do_mlp(0);      // means(63): h(63) is in HM0

  // ---------------- final h, c ----------------
  if (w < 4) {
    float* hout = out + (size_t)SEQ * BATCH * ACT;
    float* cout = hout + (size_t)BATCH * HID;
    #pragma unroll
    for (int q = 0; q < 4; ++q) {
      int r = lg * 4 + q;
      hout[(size_t)(b0 + r) * HID + j] = hlast[q];   // h(63) unmasked
      cout[(size_t)(b0 + r) * HID + j] = creg[q];    // c(63) unmasked
    }
  }
}

extern "C" void kernel_launch(void* const* d_in, const int* in_sizes, int n_in,
                              void* d_out, int out_size, void* d_ws, size_t ws_size,
                              hipStream_t stream) {
  (void)in_sizes; (void)n_in; (void)d_ws; (void)ws_size; (void)out_size;
  lstm_policy<<<dim3(NWG), dim3(NT), 0, stream>>>(
      (const float*)d_in[0], (const float*)d_in[1], (const float*)d_in[2],
      (const float*)d_in[3], (const float*)d_in[4], (const float*)d_in[5],
      (const float*)d_in[6], (const float*)d_in[7], (const float*)d_in[8],
      (const float*)d_in[9], (const float*)d_in[10], (const int*)d_in[11],
      (float*)d_out);
}